// Round 13
// baseline (93.649 us; speedup 1.0000x reference)
//
#include <hip/hip_runtime.h>
#include <hip/hip_bf16.h>

#define L_N 64
#define T_N 8192
#define K_N 128
#define N_N 128
#define BM  128    // rows per block: 64KB LDS, 1024 thr -> 2 blocks/CU = 32 waves/CU
#define NT_TILE0 56  // tiles >= this are nt-loaded (L3-bypass): 8/64 of x = 33.5MB
                     // -> cached slice 235MB + ~6MB w/wf fits the 256MB L3 exactly

typedef __attribute__((ext_vector_type(8))) short short8;   // 8 bf16 = 4 VGPR
typedef __attribute__((ext_vector_type(4))) float f32x4;    // MFMA acc / native float4

__device__ __forceinline__ unsigned short f2bf(float f) {
    union { float f; unsigned u; } c; c.f = f;
    return (unsigned short)((c.u + 0x7fffu + ((c.u >> 16) & 1u)) >> 16);  // RNE
}

// Prepass: w [L][K][N] fp32 -> pre-fragmented bf16  wf[l][ni][kk][lane][j]
//   element (l,ni,kk,lane,j) = w[l][ kk*32 + (lane>>4)*8 + j ][ ni*16 + (lane&15) ]
// (verified R2-R12). Main kernel stages wf[l] to LDS as a LINEAR copy; fragment
// reads are lane-consecutive 16B -> conflict-free by construction.
__global__ __launch_bounds__(256) void wfrag_kernel(const float* __restrict__ w,
                                                    unsigned short* __restrict__ wf) {
    __shared__ float lds[K_N * 129];            // +1 pad, 66 KB
    const int l = blockIdx.x;
    const float* wl = w + (size_t)l * (K_N * N_N);
    const int tid = threadIdx.x;
    #pragma unroll
    for (int i = 0; i < 16; ++i) {
        int f = i * 256 + tid;                  // float4 idx, coalesced
        float4 v = ((const float4*)wl)[f];
        int k = f >> 5, n = (f & 31) * 4;
        lds[k * 129 + n + 0] = v.x;
        lds[k * 129 + n + 1] = v.y;
        lds[k * 129 + n + 2] = v.z;
        lds[k * 129 + n + 3] = v.w;
    }
    __syncthreads();
    unsigned short* o = wf + (size_t)l * (N_N * K_N);
    #pragma unroll
    for (int c = 0; c < 16; ++c) {
        int chunk = c * 256 + tid;              // ushort4 idx, coalesced write
        int j0   = (chunk & 1) * 4;
        int lane = (chunk >> 1) & 63;
        int kk   = (chunk >> 7) & 3;
        int ni   = chunk >> 9;
        int n  = ni * 16 + (lane & 15);
        int kb = kk * 32 + (lane >> 4) * 8 + j0;
        ushort4 ov;
        ov.x = f2bf(lds[(kb + 0) * 129 + n]);
        ov.y = f2bf(lds[(kb + 1) * 129 + n]);
        ov.z = f2bf(lds[(kb + 2) * 129 + n]);
        ov.w = f2bf(lds[(kb + 3) * 129 + n]);
        ((ushort4*)o)[chunk] = ov;
    }
}

// Main: R12 champion (BM=128, 1024 thr, 64KB LDS, 32 waves/CU, nt out stores)
// + ONE change: L3 CACHE PARTITIONING. x is exactly 256MiB = L3 capacity, so
// the cyclic replay re-scan thrashes (R3: only 47% hit). Tiles >= NT_TILE0 use
// nontemporal loads (no L3 allocate) -> the remaining 235MB slice + w/wf fits
// under 256MB and stays resident across replays (~100% hits), trading ~34MB of
// forced misses for ~100MB of thrash misses.
__global__ __launch_bounds__(1024, 8) void gl_kernel(const float* __restrict__ x,
                                                     const unsigned short* __restrict__ wf,
                                                     const float* __restrict__ bias,
                                                     float* __restrict__ out) {
    __shared__ __align__(16) char smem[65536];
    unsigned short* xs  = (unsigned short*)smem;            // 32KB: 128 x-rows bf16, swizzled
    unsigned short* wsh = (unsigned short*)(smem + 32768);  // 32KB: w fragments, linear

    const int tid  = threadIdx.x;
    const int lane = tid & 63;
    const int wid  = tid >> 6;                  // 0..15
    const int lr   = lane & 15;
    const int lg   = lane >> 4;
    const int ws   = wid >> 1;                  // row strip 0..7 (16 rows each)
    const int ch   = wid & 1;                   // column half 0..1 (64 cols each)

    const int bid  = blockIdx.x;                // 4096 blocks = 64 layers x 64 tiles
    const int l    = bid >> 6;
    const int tile = bid & 63;
    const float* xg = x + ((size_t)l * T_N + (size_t)tile * BM) * K_N;
    const unsigned short* wl = wf + (size_t)l * (N_N * K_N);

    // stage x: 128 rows fp32 (64KB) = 4 f32x4/thread, coalesced; swizzled bf16
    // writes. Block-uniform branch: nt loads for the partitioned-out slice.
    const f32x4* xg4 = (const f32x4*)xg;
    if (tile >= NT_TILE0) {
        #pragma unroll
        for (int i = 0; i < 4; ++i) {
            int f = i * 1024 + tid;             // float4 index, 4096 total
            const f32x4 v = __builtin_nontemporal_load(xg4 + f);
            int row = f >> 5;                   // 0..127
            int kc  = (f & 31) * 4;
            union { unsigned short s[4]; unsigned long long u; } p;
            p.s[0] = f2bf(v[0]); p.s[1] = f2bf(v[1]);
            p.s[2] = f2bf(v[2]); p.s[3] = f2bf(v[3]);
            int us = (row * K_N + kc) ^ ((row & 7) << 3);
            *(unsigned long long*)&xs[us] = p.u;
        }
    } else {
        #pragma unroll
        for (int i = 0; i < 4; ++i) {
            int f = i * 1024 + tid;
            const f32x4 v = xg4[f];
            int row = f >> 5;
            int kc  = (f & 31) * 4;
            union { unsigned short s[4]; unsigned long long u; } p;
            p.s[0] = f2bf(v[0]); p.s[1] = f2bf(v[1]);
            p.s[2] = f2bf(v[2]); p.s[3] = f2bf(v[3]);
            int us = (row * K_N + kc) ^ ((row & 7) << 3);
            *(unsigned long long*)&xs[us] = p.u;
        }
    }
    // stage w: linear 32KB copy (2048 x 16B, 2/thread), conflict-free both sides
    #pragma unroll
    for (int i = 0; i < 2; ++i) {
        int c = i * 1024 + tid;
        ((short8*)wsh)[c] = ((const short8*)wl)[c];
    }
    __syncthreads();

    // MFMA: wave computes 16 rows (strip ws) x 64 cols (half ch)
    f32x4 acc[4];
    #pragma unroll
    for (int q = 0; q < 4; ++q)
        acc[q] = (f32x4){0.f, 0.f, 0.f, 0.f};
    const int row = ws * 16 + lr;
    #pragma unroll
    for (int kk = 0; kk < 4; ++kk) {
        const short8 xb = *(const short8*)&xs[(row * K_N + kk * 32 + lg * 8) ^ ((row & 7) << 3)];
        #pragma unroll
        for (int q = 0; q < 4; ++q) {
            const int ni = ch * 4 + q;
            const short8 wv = ((const short8*)wsh)[(ni * 4 + kk) * 64 + lane];
            acc[q] = __builtin_amdgcn_mfma_f32_16x16x32_bf16(wv, xb, acc[q], 0, 0, 0);
        }
    }
    __syncthreads();                            // all fragment reads done; LDS reusable

    // epilogue: bias -> wave-private 4KB window transpose -> 256B-segment NT stores
    const float* bl = bias + l * N_N;
    f32x4* osm = (f32x4*)(smem + wid * 4096);   // 16 rows x 16 f4
    #pragma unroll
    for (int q = 0; q < 4; ++q) {
        const int ni = ch * 4 + q;
        const float4 bv = *(const float4*)(bl + ni * 16 + lg * 4);
        f32x4 r;
        r[0] = acc[q][0] + bv.x;
        r[1] = acc[q][1] + bv.y;
        r[2] = acc[q][2] + bv.z;
        r[3] = acc[q][3] + bv.w;
        osm[lr * 16 + ((q * 4 + lg) ^ lr)] = r; // XOR-swizzled, row=lr
    }
    f32x4* og4 = (f32x4*)(out + ((size_t)l * T_N + (size_t)tile * BM + ws * 16) * N_N);
    #pragma unroll
    for (int q2 = 0; q2 < 4; ++q2) {            // 4 rows x 256B contiguous per inst
        const int fi = q2 * 64 + lane;
        const int rr = fi >> 4, cc = fi & 15;
        const f32x4 v = osm[rr * 16 + (cc ^ rr)];
        __builtin_nontemporal_store(v, &og4[(size_t)rr * 32 + ch * 16 + cc]);
    }
}

extern "C" void kernel_launch(void* const* d_in, const int* in_sizes, int n_in,
                              void* d_out, int out_size, void* d_ws, size_t ws_size,
                              hipStream_t stream) {
    const float* x = (const float*)d_in[0];
    const float* w = (const float*)d_in[1];
    const float* b = (const float*)d_in[2];
    float* out = (float*)d_out;
    unsigned short* wf = (unsigned short*)d_ws;   // 2 MB scratch, rewritten every call

    wfrag_kernel<<<L_N, 256, 0, stream>>>(w, wf);
    gl_kernel<<<L_N * (T_N / BM), 1024, 0, stream>>>(x, wf, b, out);
}

// Round 14
// 93.512 us; speedup vs baseline: 1.0015x; 1.0015x over previous
//
#include <hip/hip_runtime.h>
#include <hip/hip_bf16.h>

#define L_N 64
#define T_N 8192
#define K_N 128
#define N_N 128
#define BM  128    // rows per block: 64KB LDS, 1024 thr -> 2 blocks/CU = 32 waves/CU

typedef __attribute__((ext_vector_type(8))) short short8;   // 8 bf16 = 4 VGPR
typedef __attribute__((ext_vector_type(4))) float f32x4;    // MFMA acc / native float4

__device__ __forceinline__ unsigned short f2bf(float f) {
    union { float f; unsigned u; } c; c.f = f;
    return (unsigned short)((c.u + 0x7fffu + ((c.u >> 16) & 1u)) >> 16);  // RNE
}

// Prepass: w [L][K][N] fp32 -> pre-fragmented bf16  wf[l][ni][kk][lane][j]
//   element (l,ni,kk,lane,j) = w[l][ kk*32 + (lane>>4)*8 + j ][ ni*16 + (lane&15) ]
// (layout verified R2-R13). NOW 256 blocks (was 64): block = (layer, K-quarter).
// kk == quarter exactly (kb = kk*32 + ...), so each block stages 32 w-rows and
// emits all fragments with kk = qd — every CU participates, prepass ~1.5us.
__global__ __launch_bounds__(256) void wfrag_kernel(const float* __restrict__ w,
                                                    unsigned short* __restrict__ wf) {
    __shared__ float lds[32 * 129];             // 32 rows, +1 pad, 16.5 KB
    const int l  = blockIdx.x >> 2;
    const int qd = blockIdx.x & 3;              // K-quarter = kk value
    const float* wq = w + (size_t)l * (K_N * N_N) + (size_t)qd * 32 * N_N;
    const int tid = threadIdx.x;
    #pragma unroll
    for (int i = 0; i < 4; ++i) {
        int f = i * 256 + tid;                  // float4 idx over 32x128 quarter
        float4 v = ((const float4*)wq)[f];
        int k = f >> 5, n = (f & 31) * 4;       // k local 0..31
        lds[k * 129 + n + 0] = v.x;
        lds[k * 129 + n + 1] = v.y;
        lds[k * 129 + n + 2] = v.z;
        lds[k * 129 + n + 3] = v.w;
    }
    __syncthreads();
    unsigned short* o = wf + (size_t)l * (N_N * K_N);
    #pragma unroll
    for (int i = 0; i < 4; ++i) {
        int lc   = i * 256 + tid;               // local chunk 0..1023 (ushort4)
        int j0   = (lc & 1) * 4;
        int lane = (lc >> 1) & 63;
        int ni   = lc >> 7;                     // 0..7
        int n   = ni * 16 + (lane & 15);
        int kbl = (lane >> 4) * 8 + j0;         // local row 0..31 (kb - qd*32)
        ushort4 ov;
        ov.x = f2bf(lds[(kbl + 0) * 129 + n]);
        ov.y = f2bf(lds[(kbl + 1) * 129 + n]);
        ov.z = f2bf(lds[(kbl + 2) * 129 + n]);
        ov.w = f2bf(lds[(kbl + 3) * 129 + n]);
        // global chunk = ni*512 + kk*128 + lane*2 + j0/4  (kk = qd)
        ((ushort4*)o)[ni * 512 + qd * 128 + lane * 2 + (j0 >> 2)] = ov;
    }
}

// Main: unchanged R12/R13 champion — BM=128, 1024 thr, 64KB LDS, 2 blocks/CU
// = 32 waves/CU, lockstep phases, wave-private transpose epilogue, nt stores.
__global__ __launch_bounds__(1024, 8) void gl_kernel(const float* __restrict__ x,
                                                     const unsigned short* __restrict__ wf,
                                                     const float* __restrict__ bias,
                                                     float* __restrict__ out) {
    __shared__ __align__(16) char smem[65536];
    unsigned short* xs  = (unsigned short*)smem;            // 32KB: 128 x-rows bf16, swizzled
    unsigned short* wsh = (unsigned short*)(smem + 32768);  // 32KB: w fragments, linear

    const int tid  = threadIdx.x;
    const int lane = tid & 63;
    const int wid  = tid >> 6;                  // 0..15
    const int lr   = lane & 15;
    const int lg   = lane >> 4;
    const int ws   = wid >> 1;                  // row strip 0..7 (16 rows each)
    const int ch   = wid & 1;                   // column half 0..1 (64 cols each)

    const int bid  = blockIdx.x;                // 4096 blocks = 64 layers x 64 tiles
    const int l    = bid >> 6;
    const int tile = bid & 63;
    const float* xg = x + ((size_t)l * T_N + (size_t)tile * BM) * K_N;
    const unsigned short* wl = wf + (size_t)l * (N_N * K_N);

    // stage x: 128 rows fp32 (64KB) = 4 float4/thread, coalesced; swizzled bf16 writes
    #pragma unroll
    for (int i = 0; i < 4; ++i) {
        int f = i * 1024 + tid;                 // float4 index, 4096 total
        const f32x4 v = ((const f32x4*)xg)[f];
        int row = f >> 5;                       // 0..127
        int kc  = (f & 31) * 4;
        union { unsigned short s[4]; unsigned long long u; } p;
        p.s[0] = f2bf(v[0]); p.s[1] = f2bf(v[1]); p.s[2] = f2bf(v[2]); p.s[3] = f2bf(v[3]);
        int us = (row * K_N + kc) ^ ((row & 7) << 3);
        *(unsigned long long*)&xs[us] = p.u;
    }
    // stage w: linear 32KB copy (2048 x 16B, 2/thread), conflict-free both sides
    #pragma unroll
    for (int i = 0; i < 2; ++i) {
        int c = i * 1024 + tid;
        ((short8*)wsh)[c] = ((const short8*)wl)[c];
    }
    __syncthreads();

    // MFMA: wave computes 16 rows (strip ws) x 64 cols (half ch)
    f32x4 acc[4];
    #pragma unroll
    for (int q = 0; q < 4; ++q)
        acc[q] = (f32x4){0.f, 0.f, 0.f, 0.f};
    const int row = ws * 16 + lr;
    #pragma unroll
    for (int kk = 0; kk < 4; ++kk) {
        const short8 xb = *(const short8*)&xs[(row * K_N + kk * 32 + lg * 8) ^ ((row & 7) << 3)];
        #pragma unroll
        for (int q = 0; q < 4; ++q) {
            const int ni = ch * 4 + q;
            const short8 wv = ((const short8*)wsh)[(ni * 4 + kk) * 64 + lane];
            acc[q] = __builtin_amdgcn_mfma_f32_16x16x32_bf16(wv, xb, acc[q], 0, 0, 0);
        }
    }
    __syncthreads();                            // all fragment reads done; LDS reusable

    // epilogue: bias -> wave-private 4KB window transpose -> 256B-segment NT stores
    const float* bl = bias + l * N_N;
    f32x4* osm = (f32x4*)(smem + wid * 4096);   // 16 rows x 16 f4
    #pragma unroll
    for (int q = 0; q < 4; ++q) {
        const int ni = ch * 4 + q;
        const float4 bv = *(const float4*)(bl + ni * 16 + lg * 4);
        f32x4 r;
        r[0] = acc[q][0] + bv.x;
        r[1] = acc[q][1] + bv.y;
        r[2] = acc[q][2] + bv.z;
        r[3] = acc[q][3] + bv.w;
        osm[lr * 16 + ((q * 4 + lg) ^ lr)] = r; // XOR-swizzled, row=lr
    }
    f32x4* og4 = (f32x4*)(out + ((size_t)l * T_N + (size_t)tile * BM + ws * 16) * N_N);
    #pragma unroll
    for (int q2 = 0; q2 < 4; ++q2) {            // 4 rows x 256B contiguous per inst
        const int fi = q2 * 64 + lane;
        const int rr = fi >> 4, cc = fi & 15;
        const f32x4 v = osm[rr * 16 + (cc ^ rr)];
        __builtin_nontemporal_store(v, &og4[(size_t)rr * 32 + ch * 16 + cc]);
    }
}

extern "C" void kernel_launch(void* const* d_in, const int* in_sizes, int n_in,
                              void* d_out, int out_size, void* d_ws, size_t ws_size,
                              hipStream_t stream) {
    const float* x = (const float*)d_in[0];
    const float* w = (const float*)d_in[1];
    const float* b = (const float*)d_in[2];
    float* out = (float*)d_out;
    unsigned short* wf = (unsigned short*)d_ws;   // 2 MB scratch, rewritten every call

    wfrag_kernel<<<L_N * 4, 256, 0, stream>>>(w, wf);
    gl_kernel<<<L_N * (T_N / BM), 1024, 0, stream>>>(x, wf, b, out);
}